// Round 12
// baseline (254.033 us; speedup 1.0000x reference)
//
#include <hip/hip_runtime.h>

typedef float vf2 __attribute__((ext_vector_type(2)));

__device__ __forceinline__ vf2 cmulv(vf2 a, vf2 b){
  vf2 br; br.x = -b.y; br.y = b.x;
  return a.x*b + a.y*br;
}

// ---------------- X-macro index lists ----------------
#define FE32(F) F(0) F(1) F(2) F(3) F(4) F(5) F(6) F(7) F(8) F(9) F(10) F(11) \
 F(12) F(13) F(14) F(15) F(16) F(17) F(18) F(19) F(20) F(21) F(22) F(23) \
 F(24) F(25) F(26) F(27) F(28) F(29) F(30) F(31)
#define FE64(F) FE32(F) F(32) F(33) F(34) F(35) F(36) F(37) F(38) F(39) \
 F(40) F(41) F(42) F(43) F(44) F(45) F(46) F(47) F(48) F(49) F(50) F(51) \
 F(52) F(53) F(54) F(55) F(56) F(57) F(58) F(59) F(60) F(61) F(62) F(63)

// butterfly pair lists: (i, i | 1<<lb) for each i with bit lb clear
#define L0(F) F(0,1) F(2,3) F(4,5) F(6,7) F(8,9) F(10,11) F(12,13) F(14,15) \
 F(16,17) F(18,19) F(20,21) F(22,23) F(24,25) F(26,27) F(28,29) F(30,31) \
 F(32,33) F(34,35) F(36,37) F(38,39) F(40,41) F(42,43) F(44,45) F(46,47) \
 F(48,49) F(50,51) F(52,53) F(54,55) F(56,57) F(58,59) F(60,61) F(62,63)
#define L1(F) F(0,2) F(1,3) F(4,6) F(5,7) F(8,10) F(9,11) F(12,14) F(13,15) \
 F(16,18) F(17,19) F(20,22) F(21,23) F(24,26) F(25,27) F(28,30) F(29,31) \
 F(32,34) F(33,35) F(36,38) F(37,39) F(40,42) F(41,43) F(44,46) F(45,47) \
 F(48,50) F(49,51) F(52,54) F(53,55) F(56,58) F(57,59) F(60,62) F(61,63)
#define L2(F) F(0,4) F(1,5) F(2,6) F(3,7) F(8,12) F(9,13) F(10,14) F(11,15) \
 F(16,20) F(17,21) F(18,22) F(19,23) F(24,28) F(25,29) F(26,30) F(27,31) \
 F(32,36) F(33,37) F(34,38) F(35,39) F(40,44) F(41,45) F(42,46) F(43,47) \
 F(48,52) F(49,53) F(50,54) F(51,55) F(56,60) F(57,61) F(58,62) F(59,63)
#define L3(F) F(0,8) F(1,9) F(2,10) F(3,11) F(4,12) F(5,13) F(6,14) F(7,15) \
 F(16,24) F(17,25) F(18,26) F(19,27) F(20,28) F(21,29) F(22,30) F(23,31) \
 F(32,40) F(33,41) F(34,42) F(35,43) F(36,44) F(37,45) F(38,46) F(39,47) \
 F(48,56) F(49,57) F(50,58) F(51,59) F(52,60) F(53,61) F(54,62) F(55,63)
#define L4(F) F(0,16) F(1,17) F(2,18) F(3,19) F(4,20) F(5,21) F(6,22) F(7,23) \
 F(8,24) F(9,25) F(10,26) F(11,27) F(12,28) F(13,29) F(14,30) F(15,31) \
 F(32,48) F(33,49) F(34,50) F(35,51) F(36,52) F(37,53) F(38,54) F(39,55) \
 F(40,56) F(41,57) F(42,58) F(43,59) F(44,60) F(45,61) F(46,62) F(47,63)
#define L5(F) F(0,32) F(1,33) F(2,34) F(3,35) F(4,36) F(5,37) F(6,38) F(7,39) \
 F(8,40) F(9,41) F(10,42) F(11,43) F(12,44) F(13,45) F(14,46) F(15,47) \
 F(16,48) F(17,49) F(18,50) F(19,51) F(20,52) F(21,53) F(22,54) F(23,55) \
 F(24,56) F(25,57) F(26,58) F(27,59) F(28,60) F(29,61) F(30,62) F(31,63)

// merged-diagonal angle for wire j of diagonal d (wave-uniform)
#define ALPHA(d, j) (((d) & 1) \
  ? (W[((((d)>>1)*2+1)*12+(j))*3+0] + W[((((d)>>1)*2+0)*12+(j))*3+2]) \
  : (W[((((d)>>1)*2+0)*12+(j))*3+0] + xr[(j)] + W[(((((d)>>1)-1)*2+1)*12+(j))*3+2]))

// ---- RY butterfly on named SSA values: 4 v_pk ops, zero marshaling ----
#define BF(i,j) { vf2 a_ = s##i, b_ = s##j; \
  s##i = c_*a_ - sn_*b_; s##j = sn_*a_ + c_*b_; }

#define GLAYER(sl, par, lb, LIST) { \
  const int wire_ = (par) ? (5 - (lb)) : (11 - (lb)); \
  vf2 cs_ = scsl[(sl)*12 + wire_]; \
  const float c_ = cs_.x, sn_ = cs_.y; \
  LIST(BF) }

#define GATES6(sl, par) do{ \
  GLAYER(sl, par, 0, L0) GLAYER(sl, par, 1, L1) GLAYER(sl, par, 2, L2) \
  GLAYER(sl, par, 3, L3) GLAYER(sl, par, 4, L4) GLAYER(sl, par, 5, L5) \
}while(0)

// ---- 64x64 lane<->reg transpose via two XOR-swizzled 32x32 quadrant bufs ----
// bufA = tbuf[0..1023], bufB = tbuf[1024..2047]. ORDERING LOAD-BEARING:
// low-lane region BEFORE high-lane region; sequential guarded ifs + fences
// (divergent if/else arm order is compiler-chosen -> R8 failure; R10 fix).
#define T1W(w)   tbuf[qoff_ + (ul_ << 5) + (((w) ^ ul_) & 31)] = s##w;
#define T2R(w)   s##w = tbuf[((w) << 5) + ((ul_ ^ (w)) & 31)];
#define T3W(w,W) tbuf[(ul_ << 5) + (((w) ^ ul_) & 31)] = s##W;
#define T4R(w,W) s##W = tbuf[1024 + ((w) << 5) + ((ul_ ^ (w)) & 31)];
#define T5W(w,W) tbuf[1024 + (ul_ << 5) + (((w) ^ ul_) & 31)] = s##W;

#define TRANSPOSE() do{ \
  const int qoff_ = (u < 32) ? 0 : 1024; \
  const int ul_ = u & 31; \
  FE32(T1W)                      /* T1: all lanes save regs 0..31 */ \
  asm volatile("" ::: "memory"); \
  if (u < 32){ \
    FE32(T2R)                    /* T2: new 0..31 = B00^T  (bufA) */ \
    L5(T3W)                      /* T3: save old 32..63 -> bufA   */ \
    L5(T4R)                      /* T4: new 32..63 = B10^T (bufB) */ \
  } \
  asm volatile("" ::: "memory"); \
  if (u >= 32){ \
    L5(T5W)                      /* T5: save old 32..63 -> bufB   */ \
    FE32(T2R)                    /* T6a: new 0..31 = B01^T (bufA) */ \
    L5(T4R)                      /* T6b: new 32..63 = B11^T(bufB) */ \
  } \
  asm volatile("" ::: "memory"); \
}while(0)

// ---- merged diagonal: reg part from tabs (literal-w sign bits fold) ----
#define DGP1(w) { vf2 dph_ = tabs[dm1_][(w)]; \
  int sx_ = (((w) & 1) * u5_) ^ ((((w) >> 5) & 1) * u0_); \
  vf2 t_ = cmulv(s##w, dph_); s##w = cmulv(t_, sx_ ? lpn_ : lp_); }
#define DGP0(w) { vf2 dph_ = tabs[dm1_][(w)]; \
  int sx_ = ((((w) >> 5) & 1) * u1_) ^ ((((w) >> 4) & 1) * u0_) \
          ^ ((((w) >> 1) & 1) * u5_) ^ (((w) & 1) * u4_); \
  vf2 t_ = cmulv(s##w, dph_); s##w = cmulv(t_, sx_ ? lpn_ : lp_); }

#define DIAG(d, par) do{ \
  const int dm1_ = (d) - 1; \
  vf2 lp_ = (d)==1 ? lp1v : ((d)==2 ? lp2v : ((d)==3 ? lp3v : ((d)==4 ? lp4v : lp5v))); \
  vf2 lpn_ = -lp_; \
  const int u0_ = u & 1, u1_ = (u >> 1) & 1, u4_ = (u >> 4) & 1, u5_ = (u >> 5) & 1; \
  if (par){ FE64(DGP1) } else { FE64(DGP0) } \
}while(0)

#define DECL(w) vf2 s##w = {0.f, 0.f};
#define MME(w) { float re_ = s##w.x, im_ = s##w.y; float pr_ = re_*re_ + im_*im_; \
  P += pr_; \
  mm0 += ((w) & 32) ? -pr_ : pr_; mm1 += ((w) & 16) ? -pr_ : pr_; \
  mm2 += ((w) &  8) ? -pr_ : pr_; mm3 += ((w) &  4) ? -pr_ : pr_; \
  mm4 += ((w) &  2) ? -pr_ : pr_; mm5 += ((w) &  1) ? -pr_ : pr_; }

__global__ __attribute__((amdgpu_flat_work_group_size(64,64)))
__attribute__((amdgpu_waves_per_eu(1)))
// min=1 is the only proven no-spill config (R7/R11). min>=2 caps VGPR at 128
// and spills the 128-reg state (R9/R10: 1.7 GB scratch, 690 us).
void qiddm_wave(const float* __restrict__ gx,
                const float* __restrict__ gcw,
                const float* __restrict__ gcb,
                const float* __restrict__ gw1,
                const float* __restrict__ glw,
                const float* __restrict__ glb,
                float* __restrict__ gout)
{
  // One wave per sample; 4096-amp state in 64 NAMED vf2 SSA values (s0..s63):
  // first-class <2 x float> -> direct v_pk_fma_f32, no v128 marshaling movs.
  // L0: lane u = idx bits 11..6 (wires 0..5), reg w = idx bits 5..0 (wires 6..11)
  // L1: lane u = idx bits 5..0,  reg w = idx bits 11..6
  __shared__ vf2 tbuf[2048];        // quadrant transpose buffers (aliases conv image)
  __shared__ vf2 tabs[5][64];       // reg-domain diagonal tables
  __shared__ vf2 scsl[72];          // (cos, sin) of theta/2 per (sublayer, wire)

  const int u = threadIdx.x;        // lane 0..63
  const int bid = blockIdx.x;

  float xr[12];                     // circuit inputs / expvals (constant-indexed only)
  vf2 lp1v, lp2v, lp3v, lp4v, lp5v; // lane-domain diagonal factors (registers)

  // ---------- conv 3x3 s2 p1 + bias + GAP ----------
  {
    float* img = (float*)tbuf;
#pragma unroll
    for (int i = 0; i < 4; i++){
      float4 q4 = ((const float4*)gx)[(size_t)bid * 256 + i * 64 + u];
      ((float4*)img)[i * 64 + u] = q4;
    }
    float p[4][9];
#pragma unroll
    for (int i = 0; i < 4; i++){
      int pos = u + 64 * i, oi = pos >> 4, oj = pos & 15;
#pragma unroll
      for (int ki = 0; ki < 3; ki++)
#pragma unroll
        for (int kj = 0; kj < 3; kj++){
          int ri = 2*oi - 1 + ki, cj = 2*oj - 1 + kj;
          p[i][ki*3+kj] = (ri >= 0 && ri < 32 && cj >= 0 && cj < 32) ? img[ri*32+cj] : 0.0f;
        }
    }
#pragma unroll
    for (int q = 0; q < 12; q++){
      float a = 0.0f;
#pragma unroll
      for (int e = 0; e < 9; e++){
        float wv = gcw[q*9+e];                  // uniform -> scalarized
#pragma unroll
        for (int i = 0; i < 4; i++) a += p[i][e] * wv;
      }
#pragma unroll
      for (int off = 32; off; off >>= 1) a += __shfl_xor(a, off);
      xr[q] = gcb[q] + a * (1.0f/256.0f);
    }
  }

#pragma unroll 1
  for (int n = 0; n < 2; n++){
    const float* W = gw1 + n * 216;

    // ---- RY cos/sin table (72 gates) ----
#pragma unroll
    for (int rep = 0; rep < 2; rep++){
      int e = u + rep * 64;
      if (e < 72){
        float sv, cv; __sincosf(0.5f * W[e*3+1], &sv, &cv);
        vf2 cs; cs.x = cv; cs.y = sv; scsl[e] = cs;
      }
    }

    // ---- diagonal tables: reg-domain -> LDS tabs, lane-domain -> lp regs ----
#pragma unroll
    for (int d = 1; d <= 5; d++){
      const int par = d & 1;                    // 1 -> applied in L1 (r=1), 0 -> L0 (r=2)
      const int r = par ? 1 : 2;
      {
        float ph = 0.0f;
#pragma unroll
        for (int lb = 0; lb < 6; lb++){
          int wire = par ? (5 - lb) : (11 - lb);          // reg-domain wires
          ph += ALPHA(d, wire) * ((float)((u >> lb) & 1) - 0.5f);
        }
        int idx_r = par ? (u << 6) : u;
        int y = ((idx_r << r) | (idx_r >> (12 - r))) & 0xFFF;
        int s = __popc(idx_r & y) & 1;                    // within-reg CZ parity
        float sv, cv; __sincosf(ph, &sv, &cv);
        vf2 e_; e_.x = cv; e_.y = sv; if (s) e_ = -e_;
        tabs[d-1][u] = e_;
      }
      {
        float ph = 0.0f;
#pragma unroll
        for (int lb = 0; lb < 6; lb++){
          int wire = par ? (11 - lb) : (5 - lb);          // lane-domain wires
          ph += ALPHA(d, wire) * ((float)((u >> lb) & 1) - 0.5f);
        }
        int idx_l = par ? u : (u << 6);
        int y = ((idx_l << r) | (idx_l >> (12 - r))) & 0xFFF;
        int s = __popc(idx_l & y) & 1;                    // within-lane CZ parity
        float sv, cv; __sincosf(ph, &sv, &cv);
        vf2 e_; e_.x = cv; e_.y = sv; if (s) e_ = -e_;
        if      (d == 1) lp1v = e_;
        else if (d == 2) lp2v = e_;
        else if (d == 3) lp3v = e_;
        else if (d == 4) lp4v = e_;
        else             lp5v = e_;
      }
    }

    // ---- circuit: |0>, 12 half-sublayer steps, measure ----
    FE64(DECL)                                  // s0..s63 = 0
    if (u == 0) s0.x = 1.f;                     // idx 0 = (lane 0, reg 0)

    GATES6(0, 0);                               // k=0: s0 on wires 6..11 (L0)
#pragma unroll 1
    for (int k = 1; k < 12; k++){
      const int sl  = k >> 1;
      const int par = ((k + 1) >> 1) & 1;
      if (k & 1) TRANSPOSE();                   // flip lane/reg domains
      else       DIAG(sl, par);                 // D_sl before the sublayer's 2nd half
      GATES6(sl, par);
    }

    // ---- measurement in L0 (final omega-diagonal is a pure phase: dropped) ----
    {
      float P = 0.f, mm0=0.f, mm1=0.f, mm2=0.f, mm3=0.f, mm4=0.f, mm5=0.f;
      FE64(MME)                                 // reg bits 5..0 = wires 6..11
      float mv[12];
#pragma unroll
      for (int q = 0; q < 6; q++)
        mv[q] = ((u >> (5 - q)) & 1) ? -P : P;  // wires 0..5 from lane bits
      mv[6] = mm0; mv[7] = mm1; mv[8] = mm2; mv[9] = mm3; mv[10] = mm4; mv[11] = mm5;
#pragma unroll
      for (int q = 0; q < 12; q++){
        float val = mv[q];
#pragma unroll
        for (int off = 32; off; off >>= 1) val += __shfl_xor(val, off);
        xr[q] = val;                            // uniform across lanes after butterfly
      }
    }
  }

  // ---------- final linear ----------
  {
#pragma unroll
    for (int i = 0; i < 16; i++){
      int o = i * 64 + u;
      const float4* wr = (const float4*)(glw + o * 12);   // 48B rows, 16B aligned
      float4 w0 = wr[0], w1 = wr[1], w2 = wr[2];
      float a = glb[o];
      a += xr[0]*w0.x + xr[1]*w0.y + xr[2]*w0.z + xr[3]*w0.w;
      a += xr[4]*w1.x + xr[5]*w1.y + xr[6]*w1.z + xr[7]*w1.w;
      a += xr[8]*w2.x + xr[9]*w2.y + xr[10]*w2.z + xr[11]*w2.w;
      gout[(size_t)bid * 1024 + o] = a;
    }
  }
}

extern "C" void kernel_launch(void* const* d_in, const int* in_sizes, int n_in,
                              void* d_out, int out_size, void* d_ws, size_t ws_size,
                              hipStream_t stream)
{
  (void)n_in; (void)d_ws; (void)ws_size; (void)out_size;
  const float* x  = (const float*)d_in[0];
  const float* cw = (const float*)d_in[1];
  const float* cb = (const float*)d_in[2];
  const float* w1 = (const float*)d_in[3];
  const float* lw = (const float*)d_in[4];
  const float* lb = (const float*)d_in[5];
  float* out = (float*)d_out;
  const int nb = in_sizes[0] / 1024;   // 2048 samples, one wave each
  hipLaunchKernelGGL(qiddm_wave, dim3(nb), dim3(64), 0, stream,
                     x, cw, cb, w1, lw, lb, out);
}